// Round 1
// baseline (422.450 us; speedup 1.0000x reference)
//
#include <hip/hip_runtime.h>
#include <hip/hip_bf16.h>

// Problem dims (fixed by reference): bz=16, L=2048, d=768.
// sim[b,l,m] = sum_d relu(prev@W+b)[b,l,d] * relu(after@W+b)[b,m,d]
//
// Pipeline:
//   1. wt_kernel:  Wt[n][k] = bf16(W[k][n])                      (1.1 MB ws)
//   2. gemm1 x2:   P = relu(seq @ W + b) -> bf16  [32768][768]   (48 MB ws each)
//   3. gemm2:      sim[b] = P[b] @ A[b]^T -> fp32 d_out

typedef __attribute__((ext_vector_type(8))) short  bf16x8v;
typedef __attribute__((ext_vector_type(4))) float  f32x4;
typedef __attribute__((ext_vector_type(4))) short  s16x4;
typedef __attribute__((ext_vector_type(4))) float  float4v;

__device__ __forceinline__ unsigned short f2bf(float f) {
  // round-to-nearest-even fp32 -> bf16 (inputs are finite)
  unsigned int u = __float_as_uint(f);
  u += 0x7fffu + ((u >> 16) & 1u);
  return (unsigned short)(u >> 16);
}

__device__ __forceinline__ void async_copy16(void* lds, const void* g) {
  __builtin_amdgcn_global_load_lds(
      (const __attribute__((address_space(1))) void*)g,
      (__attribute__((address_space(3))) void*)lds, 16, 0, 0);
}

// ---------------- W transpose + convert: Wt[n][k] = bf16(W[k][n]) -------------
__global__ void wt_kernel(const float* __restrict__ W, short* __restrict__ Wt) {
  int idx = blockIdx.x * 256 + threadIdx.x;   // n*768 + k
  int n = idx / 768;
  int k = idx - n * 768;
  Wt[idx] = (short)f2bf(W[k * 768 + n]);
}

// ---------------- GEMM1: Out_bf16 = relu(A_f32 @ Wt^T + bias) -----------------
// A: [M][768] fp32 (M=32768), Wt: [768][768] bf16 row=out-feat, Out: [M][768] bf16
// 128x128 tile, BK=64, 4 waves (2x2), per-wave 64x64 via 4x4 frags of 16x16x32.
__global__ __launch_bounds__(256)
void gemm1_kernel(const float* __restrict__ A, const short* __restrict__ Wt,
                  const float* __restrict__ bias, short* __restrict__ Out) {
  constexpr int K = 768, N = 768, BK = 64;
  __shared__ __align__(16) short lA[128 * BK];
  __shared__ __align__(16) short lB[128 * BK];
  const int tid  = threadIdx.x;
  const int lane = tid & 63;
  const int w    = tid >> 6;
  const int wr   = w >> 1, wc = w & 1;
  const int tm   = blockIdx.y * 128;
  const int tn   = blockIdx.x * 128;

  const int lrow = lane & 15;        // fragment row (A) / col (B)
  const int lko  = (lane >> 4) * 8;  // k sub-offset within 32

  f32x4 acc[4][4] = {};

  for (int k0 = 0; k0 < K; k0 += BK) {
    // --- stage B (Wt, bf16) via global_load_lds, 4 rounds x 1024B/wave ---
#pragma unroll
    for (int i = 0; i < 4; ++i) {
      int c   = i * 256 + tid;        // 16B chunk id, 1024 chunks = 16KB tile
      int row = c >> 3;               // 8 chunks per 64-elem row
      int col = (c & 7) * 8;
      const short* g = Wt + (size_t)(tn + row) * K + k0 + col;
      async_copy16((char*)lB + i * 4096 + w * 1024, g);
    }
    // --- stage A (fp32 -> bf16) via registers, 8 rounds ---
#pragma unroll
    for (int r = 0; r < 8; ++r) {
      int c4  = r * 256 + tid;        // float4 id, 2048 total
      int row = c4 >> 4;              // 16 float4 per row
      int col = (c4 & 15) * 4;
      float4v v = *(const float4v*)(A + (size_t)(tm + row) * K + k0 + col);
      s16x4 o;
      o[0] = (short)f2bf(v[0]); o[1] = (short)f2bf(v[1]);
      o[2] = (short)f2bf(v[2]); o[3] = (short)f2bf(v[3]);
      *(s16x4*)&lA[row * BK + col] = o;
    }
    __syncthreads();

#pragma unroll
    for (int kk = 0; kk < 2; ++kk) {
      bf16x8v af[4], bg[4];
#pragma unroll
      for (int m = 0; m < 4; ++m)
        af[m] = *(const bf16x8v*)&lA[(wr * 64 + m * 16 + lrow) * BK + kk * 32 + lko];
#pragma unroll
      for (int n = 0; n < 4; ++n)
        bg[n] = *(const bf16x8v*)&lB[(wc * 64 + n * 16 + lrow) * BK + kk * 32 + lko];
#pragma unroll
      for (int m = 0; m < 4; ++m)
#pragma unroll
        for (int n = 0; n < 4; ++n)
          acc[m][n] = __builtin_amdgcn_mfma_f32_16x16x32_bf16(af[m], bg[n], acc[m][n], 0, 0, 0);
    }
    __syncthreads();
  }

  // epilogue: bias + relu + bf16 store
#pragma unroll
  for (int n = 0; n < 4; ++n) {
    int col = tn + wc * 64 + n * 16 + lrow;
    float bv = bias[col];
#pragma unroll
    for (int m = 0; m < 4; ++m) {
      int row0 = tm + wr * 64 + m * 16 + (lane >> 4) * 4;
#pragma unroll
      for (int i = 0; i < 4; ++i) {
        float v = acc[m][n][i] + bv;
        v = fmaxf(v, 0.0f);
        Out[(size_t)(row0 + i) * N + col] = (short)f2bf(v);
      }
    }
  }
}

// ---------------- GEMM2: C[b] = P[b] @ Q[b]^T (bf16 x bf16 -> fp32) ----------
// P,Q: [16][2048][768] bf16;  C: [16][2048][2048] fp32
__global__ __launch_bounds__(256)
void gemm2_kernel(const short* __restrict__ P, const short* __restrict__ Q,
                  float* __restrict__ C) {
  constexpr int K = 768, BK = 64, LD = 2048;
  __shared__ __align__(16) short lA[128 * BK];
  __shared__ __align__(16) short lB[128 * BK];
  const int tid  = threadIdx.x;
  const int lane = tid & 63;
  const int w    = tid >> 6;
  const int wr   = w >> 1, wc = w & 1;
  const int bz   = blockIdx.z;
  const int tm   = blockIdx.y * 128;
  const int tn   = blockIdx.x * 128;

  const short* Pb = P + (size_t)bz * LD * K;
  const short* Qb = Q + (size_t)bz * LD * K;
  float*       Cb = C + (size_t)bz * LD * LD;

  const int lrow = lane & 15;
  const int lko  = (lane >> 4) * 8;

  f32x4 acc[4][4] = {};

  for (int k0 = 0; k0 < K; k0 += BK) {
#pragma unroll
    for (int i = 0; i < 4; ++i) {
      int c   = i * 256 + tid;
      int row = c >> 3;
      int col = (c & 7) * 8;
      async_copy16((char*)lA + i * 4096 + w * 1024,
                   Pb + (size_t)(tm + row) * K + k0 + col);
      async_copy16((char*)lB + i * 4096 + w * 1024,
                   Qb + (size_t)(tn + row) * K + k0 + col);
    }
    __syncthreads();

#pragma unroll
    for (int kk = 0; kk < 2; ++kk) {
      bf16x8v af[4], bg[4];
#pragma unroll
      for (int m = 0; m < 4; ++m)
        af[m] = *(const bf16x8v*)&lA[(wr * 64 + m * 16 + lrow) * BK + kk * 32 + lko];
#pragma unroll
      for (int n = 0; n < 4; ++n)
        bg[n] = *(const bf16x8v*)&lB[(wc * 64 + n * 16 + lrow) * BK + kk * 32 + lko];
#pragma unroll
      for (int m = 0; m < 4; ++m)
#pragma unroll
        for (int n = 0; n < 4; ++n)
          acc[m][n] = __builtin_amdgcn_mfma_f32_16x16x32_bf16(af[m], bg[n], acc[m][n], 0, 0, 0);
    }
    __syncthreads();
  }

#pragma unroll
  for (int m = 0; m < 4; ++m) {
    int row0 = tm + wr * 64 + m * 16 + (lane >> 4) * 4;
#pragma unroll
    for (int n = 0; n < 4; ++n) {
      int col = tn + wc * 64 + n * 16 + lrow;
#pragma unroll
      for (int i = 0; i < 4; ++i)
        Cb[(size_t)(row0 + i) * LD + col] = acc[m][n][i];
    }
  }
}

extern "C" void kernel_launch(void* const* d_in, const int* in_sizes, int n_in,
                              void* d_out, int out_size, void* d_ws, size_t ws_size,
                              hipStream_t stream) {
  const float* seq_prev  = (const float*)d_in[0];  // [16][2048][768]
  const float* seq_after = (const float*)d_in[1];  // [16][2048][768]
  const float* W         = (const float*)d_in[2];  // [768][768] (in,out)
  const float* bias      = (const float*)d_in[3];  // [768]
  float* out             = (float*)d_out;          // [16][2048][2048]

  char* ws = (char*)d_ws;
  short* Wt = (short*)ws;                                    // 768*768 bf16 = 1179648 B
  short* Pp = (short*)(ws + 1179648);                        // 16*2048*768 bf16 = 50331648 B
  short* Pa = (short*)(ws + 1179648 + 50331648);             // 16*2048*768 bf16

  // 1. W transpose+convert
  wt_kernel<<<768 * 768 / 256, 256, 0, stream>>>(W, Wt);

  // 2. feed-forward + relu for both sequences (M = 16*2048 = 32768)
  dim3 g1(6, 256);   // x = n-tiles (768/128), y = m-tiles (32768/128)
  gemm1_kernel<<<g1, 256, 0, stream>>>(seq_prev,  Wt, bias, Pp);
  gemm1_kernel<<<g1, 256, 0, stream>>>(seq_after, Wt, bias, Pa);

  // 3. batched similarity: sim[b] = P[b] @ A[b]^T
  dim3 g2(16, 16, 16);  // x = n-tile, y = m-tile, z = batch
  gemm2_kernel<<<g2, 256, 0, stream>>>(Pp, Pa, out);
}

// Round 2
// 314.846 us; speedup vs baseline: 1.3418x; 1.3418x over previous
//
#include <hip/hip_runtime.h>
#include <hip/hip_bf16.h>

// sim[b,l,m] = sum_d relu(prev@W+b)[b,l,d] * relu(after@W+b)[b,m,d]
// bz=16, L=2048, d=768.
//
// Pipeline:
//   1. wt_kernel : Wt[n][k] = bf16(W[k][n])                       (ws, 1.2 MB)
//   2. conv x2   : Sb = bf16(seq_prev ++ seq_after) [65536][768]  (in d_out as scratch)
//   3. gemm1     : Pboth = relu(Sb @ Wt^T + bias) -> bf16         (ws, 96 MB)
//   4. gemm2     : sim[b] = Pp[b] @ Pa[b]^T -> fp32 d_out (overwrites scratch)
//
// GEMM: 256x256 tile, BK=64, 8 waves (2Mx4N), double-buffered 128KB LDS,
// global_load_lds w/ pre-swizzled source (XOR (row&7)<<4), counted vmcnt(8),
// raw s_barrier, setprio around MFMA clusters.

typedef __attribute__((ext_vector_type(8))) short  bf16x8v;
typedef __attribute__((ext_vector_type(8))) short  s16x8;
typedef __attribute__((ext_vector_type(4))) float  f32x4;
typedef __attribute__((ext_vector_type(4))) float  float4v;

__device__ __forceinline__ unsigned short f2bf(float f) {
  unsigned int u = __float_as_uint(f);
  u += 0x7fffu + ((u >> 16) & 1u);
  return (unsigned short)(u >> 16);
}

__device__ __forceinline__ void async_copy16(void* lds, const void* g) {
  __builtin_amdgcn_global_load_lds(
      (const __attribute__((address_space(1))) void*)g,
      (__attribute__((address_space(3))) void*)lds, 16, 0, 0);
}

#define BAR()    asm volatile("s_barrier" ::: "memory")
#define WAITV8() asm volatile("s_waitcnt vmcnt(8)" ::: "memory")
#define WAITV0() asm volatile("s_waitcnt vmcnt(0)" ::: "memory")
#define WAITL()  do { asm volatile("s_waitcnt lgkmcnt(0)" ::: "memory"); \
                      __builtin_amdgcn_sched_barrier(0); } while (0)

// ---------------- W transpose + convert: Wt[n][k] = bf16(W[k][n]) ------------
__global__ void wt_kernel(const float* __restrict__ W, short* __restrict__ Wt) {
  int idx = blockIdx.x * 256 + threadIdx.x;   // n*768 + k
  int n = idx / 768;
  int k = idx - n * 768;
  Wt[idx] = (short)f2bf(W[k * 768 + n]);
}

// ---------------- fp32 -> bf16 conversion (vectorized 8/thread) --------------
__global__ void conv_kernel(const float* __restrict__ X, short* __restrict__ Y, int n8) {
  int stride = gridDim.x * blockDim.x;
  for (int i = blockIdx.x * blockDim.x + threadIdx.x; i < n8; i += stride) {
    const float4v* Xv = (const float4v*)X;
    float4v a = Xv[2 * i];
    float4v b = Xv[2 * i + 1];
    s16x8 o;
    o[0] = (short)f2bf(a[0]); o[1] = (short)f2bf(a[1]);
    o[2] = (short)f2bf(a[2]); o[3] = (short)f2bf(a[3]);
    o[4] = (short)f2bf(b[0]); o[5] = (short)f2bf(b[1]);
    o[6] = (short)f2bf(b[2]); o[7] = (short)f2bf(b[3]);
    ((s16x8*)Y)[i] = o;
  }
}

// ---------------- Pipelined 256x256 GEMM (C = A @ B^T), K=768 ----------------
// A: [*][768] bf16 rows tm..tm+255 ; B: [*][768] bf16 rows tn..tn+255
// EPI 0: fp32 store to C[ldc]   EPI 1: bias+relu -> bf16 store to C[ldc]
template<int EPI>
__global__ __launch_bounds__(512, 2)
void gemm_pipe(const short* __restrict__ A, const short* __restrict__ B,
               const float* __restrict__ bias, void* __restrict__ Cout,
               int ldc, long long sA, long long sB, long long sC) {
  constexpr int BK = 64, KT = 12;             // K = 768
  __shared__ __align__(16) short lA[2][256 * BK];
  __shared__ __align__(16) short lB[2][256 * BK];

  const int tid  = threadIdx.x;
  const int lane = tid & 63;
  const int w    = tid >> 6;                  // 0..7
  const int wr   = w >> 2;                    // 0..1  (M half)
  const int wc   = w & 3;                     // 0..3  (N quarter)
  const int bz   = blockIdx.z;
  const int tm   = blockIdx.y * 256;
  const int tn   = blockIdx.x * 256;

  const short* Ab = A + (size_t)bz * sA + (size_t)tm * 768;
  const short* Bb = B + (size_t)bz * sB + (size_t)tn * 768;

  const int lrow = lane & 15;                 // fragment row within 16
  const int koff = (lane >> 4) * 16;          // byte offset of lane's k-slice
  const int sx   = (lrow & 7) << 4;           // XOR swizzle term (row&7 == lrow&7)
  const int arow = wr * 128 + lrow;           // A row base for this lane
  const int brow = wc * 64 + lrow;            // B row base for this lane

  // staging: thread covers physical LDS slot c*16; source col = phys ^ swizzle
#define STAGE(buf, k0)                                                        \
  {                                                                           \
    _Pragma("unroll")                                                         \
    for (int j = 0; j < 4; ++j) {                                             \
      int c    = j * 512 + tid;                                               \
      int row  = c >> 3;                                                      \
      int colb = ((c & 7) * 16) ^ ((row & 7) << 4);                           \
      async_copy16((char*)lA[buf] + j * 8192 + w * 1024,                      \
                   (const char*)(Ab + (size_t)row * 768 + (k0)) + colb);      \
      async_copy16((char*)lB[buf] + j * 8192 + w * 1024,                      \
                   (const char*)(Bb + (size_t)row * 768 + (k0)) + colb);      \
    }                                                                         \
  }

#define LOAD_FRAGS(buf, kk)                                                   \
  {                                                                           \
    const char* bA = (const char*)lA[buf];                                    \
    const char* bB = (const char*)lB[buf];                                    \
    const int kx = ((kk) * 64 + koff) ^ sx;                                   \
    _Pragma("unroll")                                                         \
    for (int m = 0; m < 8; ++m)                                               \
      af[m] = *(const bf16x8v*)(bA + (arow + m * 16) * 128 + kx);             \
    _Pragma("unroll")                                                         \
    for (int n = 0; n < 4; ++n)                                               \
      bg[n] = *(const bf16x8v*)(bB + (brow + n * 16) * 128 + kx);             \
  }

#define MFMA_PHASE()                                                          \
  {                                                                           \
    __builtin_amdgcn_s_setprio(1);                                            \
    _Pragma("unroll")                                                         \
    for (int m = 0; m < 8; ++m)                                               \
      _Pragma("unroll")                                                       \
      for (int n = 0; n < 4; ++n)                                             \
        acc[m][n] = __builtin_amdgcn_mfma_f32_16x16x32_bf16(                  \
            af[m], bg[n], acc[m][n], 0, 0, 0);                                \
    __builtin_amdgcn_s_setprio(0);                                            \
  }

  f32x4 acc[8][4] = {};
  bf16x8v af[8], bg[4];

  // prologue: K-tile 0 -> buf0, K-tile 1 -> buf1  (16 loads in flight)
  STAGE(0, 0);
  STAGE(1, BK);

  int cur = 0;
  for (int kt = 0; kt < KT; ++kt) {
    if (kt < KT - 1) { WAITV8(); } else { WAITV0(); }   // my K-tile kt staged
    BAR();                                              // everyone's staged

    // phase 0: reads + MFMA
    LOAD_FRAGS(cur, 0);
    WAITL();
    MFMA_PHASE();

    // phase 1 reads, then free the buffer for prefetch
    LOAD_FRAGS(cur, 1);
    WAITL();
    BAR();                                              // all reads of buf[cur] done
    if (kt < KT - 2) STAGE(cur, (kt + 2) * BK);         // prefetch kt+2 (8 loads)
    MFMA_PHASE();

    cur ^= 1;
  }

  // epilogue
#pragma unroll
  for (int m = 0; m < 8; ++m) {
    int row0 = tm + wr * 128 + m * 16 + (lane >> 4) * 4;
#pragma unroll
    for (int n = 0; n < 4; ++n) {
      int col = tn + wc * 64 + n * 16 + lrow;
      if (EPI == 0) {
        float* C = (float*)Cout + (size_t)bz * sC;
#pragma unroll
        for (int i = 0; i < 4; ++i)
          C[(size_t)(row0 + i) * ldc + col] = acc[m][n][i];
      } else {
        short* C = (short*)Cout + (size_t)bz * sC;
        float bv = bias[col];
#pragma unroll
        for (int i = 0; i < 4; ++i) {
          float v = fmaxf(acc[m][n][i] + bv, 0.0f);
          C[(size_t)(row0 + i) * ldc + col] = (short)f2bf(v);
        }
      }
    }
  }
#undef STAGE
#undef LOAD_FRAGS
#undef MFMA_PHASE
}

extern "C" void kernel_launch(void* const* d_in, const int* in_sizes, int n_in,
                              void* d_out, int out_size, void* d_ws, size_t ws_size,
                              hipStream_t stream) {
  const float* seq_prev  = (const float*)d_in[0];  // [16][2048][768]
  const float* seq_after = (const float*)d_in[1];  // [16][2048][768]
  const float* W         = (const float*)d_in[2];  // [768][768] (in,out)
  const float* bias      = (const float*)d_in[3];  // [768]
  float* out             = (float*)d_out;          // [16][2048][2048] fp32

  char* ws   = (char*)d_ws;
  short* Wt  = (short*)ws;                         // 768*768*2        = 1179648 B
  short* Pb  = (short*)(ws + 1179648);             // 65536*768*2      = 100663296 B
  // Sb (bf16 inputs) lives in d_out scratch space (dead until gemm2 overwrites)
  short* Sb  = (short*)d_out;                      // 65536*768*2 = 96 MB << 256 MB

  constexpr int NSEQ = 16 * 2048 * 768;            // elems per sequence
  constexpr int N8   = NSEQ / 8;

  // 1. W transpose + convert
  wt_kernel<<<768 * 768 / 256, 256, 0, stream>>>(W, Wt);

  // 2. convert both sequences to bf16 (into d_out scratch)
  conv_kernel<<<2048, 256, 0, stream>>>(seq_prev,  Sb,        N8);
  conv_kernel<<<2048, 256, 0, stream>>>(seq_after, Sb + NSEQ, N8);

  // 3. feed-forward + relu, both seqs at once: M=65536, N=768
  dim3 g1(3, 256, 1);
  gemm_pipe<1><<<g1, 512, 0, stream>>>(Sb, Wt, bias, Pb, 768, 0, 0, 0);

  // 4. batched similarity: sim[b] = Pp[b] @ Pa[b]^T  (M=N=2048 per batch)
  dim3 g2(8, 8, 16);
  gemm_pipe<0><<<g2, 512, 0, stream>>>(Pb, Pb + NSEQ, nullptr, out,
                                       2048, 2048 * 768, 2048 * 768,
                                       2048LL * 2048);
}

// Round 5
// 304.344 us; speedup vs baseline: 1.3881x; 1.0345x over previous
//
#include <hip/hip_runtime.h>
#include <hip/hip_bf16.h>

// sim[b,l,m] = sum_d relu(prev@W+b)[b,l,d] * relu(after@W+b)[b,m,d]
// bz=16, L=2048, d=768.
//
// Pipeline:
//   1. wt_kernel : Wt[n][k] = bf16(W[k][n])                       (ws, 1.2 MB)
//   2. conv x2   : Sb = bf16(seq_prev ++ seq_after) [65536][768]  (d_out scratch)
//   3. gemm1     : Pboth = relu(Sb @ Wt^T + bias) -> bf16         (ws, 96 MB)
//   4. gemm2     : sim[b] = Pp[b] @ Pa[b]^T -> fp32 d_out
//
// GEMM: round-2 sync skeleton (proven correct): 256x256 tile, BK=64, 8 waves
// (2Mx4N), double-buffered 128KB LDS, global_load_lds w/ pre-swizzled source
// (XOR (row&7)<<4), counted vmcnt(8), 2 read/MFMA phases per K-tile.
// CHANGED vs round 2: MFMA shape 32x32x16 (same 12 frag-reads per phase feed
// 2x FLOP -> LDS pressure per FLOP halves; higher MFMA ceiling). C/D layout:
// col=lane&31, row=(reg&3)+8*(reg>>2)+4*(lane>>5)   [HW-verified m74/m101].

typedef __attribute__((ext_vector_type(8)))  short bf16x8v;
typedef __attribute__((ext_vector_type(8)))  short s16x8;
typedef __attribute__((ext_vector_type(16))) float f32x16;
typedef __attribute__((ext_vector_type(4)))  float float4v;

__device__ __forceinline__ unsigned short f2bf(float f) {
  unsigned int u = __float_as_uint(f);
  u += 0x7fffu + ((u >> 16) & 1u);
  return (unsigned short)(u >> 16);
}

__device__ __forceinline__ void async_copy16(void* lds, const void* g) {
  __builtin_amdgcn_global_load_lds(
      (const __attribute__((address_space(1))) void*)g,
      (__attribute__((address_space(3))) void*)lds, 16, 0, 0);
}

#define BAR()    asm volatile("s_barrier" ::: "memory")
#define WAITV8() asm volatile("s_waitcnt vmcnt(8)" ::: "memory")
#define WAITV0() asm volatile("s_waitcnt vmcnt(0)" ::: "memory")
#define WAITL()  do { asm volatile("s_waitcnt lgkmcnt(0)" ::: "memory"); \
                      __builtin_amdgcn_sched_barrier(0); } while (0)

// ---------------- W transpose + convert: Wt[n][k] = bf16(W[k][n]) ------------
__global__ void wt_kernel(const float* __restrict__ W, short* __restrict__ Wt) {
  int idx = blockIdx.x * 256 + threadIdx.x;   // n*768 + k
  int n = idx / 768;
  int k = idx - n * 768;
  Wt[idx] = (short)f2bf(W[k * 768 + n]);
}

// ---------------- fp32 -> bf16 conversion (vectorized 8/thread) --------------
__global__ void conv_kernel(const float* __restrict__ X, short* __restrict__ Y, int n8) {
  int stride = gridDim.x * blockDim.x;
  for (int i = blockIdx.x * blockDim.x + threadIdx.x; i < n8; i += stride) {
    const float4v* Xv = (const float4v*)X;
    float4v a = Xv[2 * i];
    float4v b = Xv[2 * i + 1];
    s16x8 o;
    o[0] = (short)f2bf(a[0]); o[1] = (short)f2bf(a[1]);
    o[2] = (short)f2bf(a[2]); o[3] = (short)f2bf(a[3]);
    o[4] = (short)f2bf(b[0]); o[5] = (short)f2bf(b[1]);
    o[6] = (short)f2bf(b[2]); o[7] = (short)f2bf(b[3]);
    ((s16x8*)Y)[i] = o;
  }
}

// ---------------- Pipelined 256x256 GEMM (C = A @ B^T), K=768 ----------------
// A: [*][768] bf16 rows tm..tm+255 ; B: [*][768] bf16 rows tn..tn+255
// EPI 0: fp32 store to C[ldc]   EPI 1: bias+relu -> bf16 store to C[ldc]
template<int EPI>
__global__ __launch_bounds__(512, 2)
void gemm_pipe(const short* __restrict__ A, const short* __restrict__ B,
               const float* __restrict__ bias, void* __restrict__ Cout,
               int ldc, long long sA, long long sB, long long sC) {
  constexpr int BK = 64, KT = 12;             // K = 768
  __shared__ __align__(16) short lA[2][256 * BK];
  __shared__ __align__(16) short lB[2][256 * BK];

  const int tid  = threadIdx.x;
  const int lane = tid & 63;
  const int w    = tid >> 6;                  // 0..7
  const int wr   = w >> 2;                    // 0..1  (M half: 128 rows)
  const int wc   = w & 3;                     // 0..3  (N quarter: 64 cols)
  const int bz   = blockIdx.z;
  const int tm   = blockIdx.y * 256;
  const int tn   = blockIdx.x * 256;

  const short* Ab = A + (size_t)bz * sA + (size_t)tm * 768;
  const short* Bb = B + (size_t)bz * sB + (size_t)tn * 768;

  const int l31  = lane & 31;                 // fragment row (A) / col (B)
  const int khb  = (lane >> 5) * 16;          // byte offset of lane's k-half (8 bf16)
  const int sx   = (lane & 7) << 4;           // XOR swizzle term (row&7 == lane&7)
  const int arow = wr * 128 + l31;            // A row base for this lane
  const int brow = wc * 64 + l31;             // B row base for this lane

  // staging: thread covers physical LDS slot c*16; source col = phys ^ swizzle
#define STAGE(buf, k0)                                                        \
  {                                                                           \
    _Pragma("unroll")                                                         \
    for (int j = 0; j < 4; ++j) {                                             \
      int c    = j * 512 + tid;                                               \
      int row  = c >> 3;                                                      \
      int colb = ((c & 7) * 16) ^ ((row & 7) << 4);                           \
      async_copy16((char*)lA[buf] + j * 8192 + w * 1024,                      \
                   (const char*)(Ab + (size_t)row * 768 + (k0)) + colb);      \
      async_copy16((char*)lB[buf] + j * 8192 + w * 1024,                      \
                   (const char*)(Bb + (size_t)row * 768 + (k0)) + colb);      \
    }                                                                         \
  }

  // per phase (kk = K-half of the 64-wide tile): 8 A-frags (4 mt x 2 ks),
  // 4 B-frags (2 nt x 2 ks); each frag = 8 bf16 = one ds_read_b128
#define LOAD_FRAGS(buf, kk)                                                   \
  {                                                                           \
    const char* bA = (const char*)lA[buf];                                    \
    const char* bB = (const char*)lB[buf];                                    \
    _Pragma("unroll")                                                         \
    for (int ks = 0; ks < 2; ++ks) {                                          \
      const int kx = ((kk) * 64 + ks * 32 + khb) ^ sx;                        \
      _Pragma("unroll")                                                       \
      for (int mt = 0; mt < 4; ++mt)                                          \
        af[mt][ks] = *(const bf16x8v*)(bA + (arow + mt * 32) * 128 + kx);     \
      _Pragma("unroll")                                                       \
      for (int nt = 0; nt < 2; ++nt)                                          \
        bg[nt][ks] = *(const bf16x8v*)(bB + (brow + nt * 32) * 128 + kx);     \
    }                                                                         \
  }

#define MFMA_PHASE()                                                          \
  {                                                                           \
    __builtin_amdgcn_s_setprio(1);                                            \
    _Pragma("unroll")                                                         \
    for (int ks = 0; ks < 2; ++ks)                                            \
      _Pragma("unroll")                                                       \
      for (int mt = 0; mt < 4; ++mt)                                          \
        _Pragma("unroll")                                                     \
        for (int nt = 0; nt < 2; ++nt)                                        \
          acc[mt][nt] = __builtin_amdgcn_mfma_f32_32x32x16_bf16(              \
              af[mt][ks], bg[nt][ks], acc[mt][nt], 0, 0, 0);                  \
    __builtin_amdgcn_s_setprio(0);                                            \
  }

  f32x16 acc[4][2] = {};
  bf16x8v af[4][2], bg[2][2];

  // prologue: K-tile 0 -> buf0, K-tile 1 -> buf1  (16 loads in flight)
  STAGE(0, 0);
  STAGE(1, BK);

  int cur = 0;
  for (int kt = 0; kt < KT; ++kt) {
    if (kt < KT - 1) { WAITV8(); } else { WAITV0(); }   // my K-tile kt staged
    BAR();                                              // everyone's staged

    // phase 0: reads + MFMA
    LOAD_FRAGS(cur, 0);
    WAITL();
    MFMA_PHASE();

    // phase 1 reads, then free the buffer for prefetch
    LOAD_FRAGS(cur, 1);
    WAITL();
    BAR();                                              // all reads of buf[cur] done
    if (kt < KT - 2) STAGE(cur, (kt + 2) * BK);         // prefetch kt+2 (8 loads)
    MFMA_PHASE();

    cur ^= 1;
  }

  // epilogue: C/D layout col=lane&31, row=(reg&3)+8*(reg>>2)+4*(lane>>5)
#pragma unroll
  for (int mt = 0; mt < 4; ++mt) {
    int rowb = tm + wr * 128 + mt * 32 + 4 * (lane >> 5);
#pragma unroll
    for (int nt = 0; nt < 2; ++nt) {
      int col = tn + wc * 64 + nt * 32 + l31;
      if (EPI == 0) {
        float* C = (float*)Cout + (size_t)bz * sC;
#pragma unroll
        for (int reg = 0; reg < 16; ++reg) {
          int row = rowb + (reg & 3) + 8 * (reg >> 2);
          C[(size_t)row * ldc + col] = acc[mt][nt][reg];
        }
      } else {
        short* C = (short*)Cout + (size_t)bz * sC;
        float bv = bias[col];
#pragma unroll
        for (int reg = 0; reg < 16; ++reg) {
          int row = rowb + (reg & 3) + 8 * (reg >> 2);
          float v = fmaxf(acc[mt][nt][reg] + bv, 0.0f);
          C[(size_t)row * ldc + col] = (short)f2bf(v);
        }
      }
    }
  }
#undef STAGE
#undef LOAD_FRAGS
#undef MFMA_PHASE
}

extern "C" void kernel_launch(void* const* d_in, const int* in_sizes, int n_in,
                              void* d_out, int out_size, void* d_ws, size_t ws_size,
                              hipStream_t stream) {
  const float* seq_prev  = (const float*)d_in[0];  // [16][2048][768]
  const float* seq_after = (const float*)d_in[1];  // [16][2048][768]
  const float* W         = (const float*)d_in[2];  // [768][768] (in,out)
  const float* bias      = (const float*)d_in[3];  // [768]
  float* out             = (float*)d_out;          // [16][2048][2048] fp32

  char* ws   = (char*)d_ws;
  short* Wt  = (short*)ws;                         // 768*768*2   = 1179648 B
  short* Pb  = (short*)(ws + 1179648);             // 65536*768*2 = 100663296 B
  short* Sb  = (short*)d_out;                      // scratch in d_out (96 MB)

  constexpr int NSEQ = 16 * 2048 * 768;
  constexpr int N8   = NSEQ / 8;

  // 1. W transpose + convert
  wt_kernel<<<768 * 768 / 256, 256, 0, stream>>>(W, Wt);

  // 2. convert both sequences to bf16 (into d_out scratch)
  conv_kernel<<<2048, 256, 0, stream>>>(seq_prev,  Sb,        N8);
  conv_kernel<<<2048, 256, 0, stream>>>(seq_after, Sb + NSEQ, N8);

  // 3. feed-forward + relu, both seqs at once: M=65536, N=768
  dim3 g1(3, 256, 1);
  gemm_pipe<1><<<g1, 512, 0, stream>>>(Sb, Wt, bias, Pb, 768, 0, 0, 0);

  // 4. batched similarity: sim[b] = Pp[b] @ Pa[b]^T  (M=N=2048 per batch)
  dim3 g2(8, 8, 16);
  gemm_pipe<0><<<g2, 512, 0, stream>>>(Pb, Pb + NSEQ, nullptr, out,
                                       2048, 2048 * 768, 2048 * 768,
                                       2048LL * 2048);
}